// Round 5
// baseline (1018.904 us; speedup 1.0000x reference)
//
#include <hip/hip_runtime.h>
#include <hip/hip_bf16.h>
#include <cstdint>

// B=4, S=2048, D=1024, NH=16, DK=64. Inputs fp32, output fp32.
// Pipeline:
//   convert: xb = bf16(x)  (+ weights -> bf16 if ws allows)
//   qkv_gemm: [Q|K|Vt] = xb @ [qw|kw|vw]^T, rope fused into Q/K epilogue
//             (Q additionally scaled by log2(e)/8), V stored transposed.
//   attn: causal flash, fixed-max softmax (exp2), K/V register prefetch,
//         Br=128/block (32/wave), Bc=64, AO aliases Q.
//   gemm_o: out = AO @ o_proj^T -> fp32

typedef __attribute__((ext_vector_type(8))) short short8;
typedef __attribute__((ext_vector_type(4))) float float4v;

#define MFMA16(a, b, c) __builtin_amdgcn_mfma_f32_16x16x32_bf16((a), (b), (c), 0, 0, 0)

__device__ __forceinline__ void glds16(const void* g, void* l) {
    __builtin_amdgcn_global_load_lds(
        (const __attribute__((address_space(1))) void*)g,
        (__attribute__((address_space(3))) void*)l, 16, 0, 0);
}

__device__ __forceinline__ unsigned short f2bf(float x) {
    union { float f; unsigned int u; } v; v.f = x;
    unsigned int r = (v.u + 0x7FFFu + ((v.u >> 16) & 1u)) >> 16;   // RNE
    return (unsigned short)r;
}

__device__ __forceinline__ short8 load8f(const float* p) {
    const float4 f0 = *(const float4*)p;
    const float4 f1 = *(const float4*)(p + 4);
    short8 r;
    r[0] = (short)f2bf(f0.x); r[1] = (short)f2bf(f0.y);
    r[2] = (short)f2bf(f0.z); r[3] = (short)f2bf(f0.w);
    r[4] = (short)f2bf(f1.x); r[5] = (short)f2bf(f1.y);
    r[6] = (short)f2bf(f1.z); r[7] = (short)f2bf(f1.w);
    return r;
}

// ---------------------------------------------------------------------------
__global__ __launch_bounds__(256) void convert_kernel(
    const float* __restrict__ in, __hip_bfloat16* __restrict__ out)
{
    const int idx = (blockIdx.x * 256 + threadIdx.x) * 8;
    *(short8*)(out + idx) = load8f(in + idx);
}

// ---------------------------------------------------------------------------
// Fused QKV GEMM. A = xb [8192 x 1024] bf16. B = one of {wq,wk,wv} [1024 x
// 1024] selected by bn region (N = 3072 virtual). 128x128 tile, BK=32,
// 4 waves, 16x16x32 MFMA, 4x4/wave, glds16 staging (BBF=1) or fp32 register
// staging for B (BBF=0). Epilogue: Q/K get rope (+ Q scale log2e/8); V is
// stored transposed into Vt[1024][8192].
// ---------------------------------------------------------------------------
template<int BBF>
__global__ __launch_bounds__(256) void qkv_gemm(
    const __hip_bfloat16* __restrict__ Abf,
    const void* __restrict__ Wq, const void* __restrict__ Wk, const void* __restrict__ Wv,
    __hip_bfloat16* __restrict__ Qp, __hip_bfloat16* __restrict__ Kp,
    __hip_bfloat16* __restrict__ Vt)
{
    __shared__ __hip_bfloat16 lA[128 * 32];
    __shared__ __hip_bfloat16 lB[128 * 32];

    const int K = 1024;
    const int bm = blockIdx.x / 24, bn = blockIdx.x % 24;
    const int widx = bn >> 3;              // 0=Q 1=K 2=V
    const int bcol0 = (bn & 7) * 128;      // col offset within the 1024-wide proj
    const void* W = (widx == 0) ? Wq : (widx == 1) ? Wk : Wv;

    const int tid = threadIdx.x;
    const int wave = tid >> 6, lane = tid & 63;
    const int wm = (wave >> 1) * 64, wn = (wave & 1) * 64;
    const int m16 = lane & 15, quad = lane >> 4;

    const int lrow = lane >> 2, lcol = (lane & 3) * 8;   // glds map
    const int srow = tid >> 2, scol = (tid & 3) * 8;     // register-path map

    float4v acc[4][4] = {};

    for (int k0 = 0; k0 < K; k0 += 32) {
        short8 rb0, rb1;
        if (!BBF) {
            const float* Wf = (const float*)W;
            rb0 = load8f(Wf + (int64_t)(bcol0 + srow) * K + scol + k0);
            rb1 = load8f(Wf + (int64_t)(bcol0 + 64 + srow) * K + scol + k0);
        }
        __syncthreads();
        {
            const __hip_bfloat16* g = Abf + (int64_t)(bm * 128 + wave * 32 + lrow) * K + lcol + k0;
            glds16(g, &lA[wave * 1024]);
            glds16(g + (int64_t)16 * K, &lA[wave * 1024 + 512]);
        }
        if (BBF) {
            const __hip_bfloat16* g = (const __hip_bfloat16*)W +
                (int64_t)(bcol0 + wave * 32 + lrow) * K + lcol + k0;
            glds16(g, &lB[wave * 1024]);
            glds16(g + (int64_t)16 * K, &lB[wave * 1024 + 512]);
        } else {
            *(short8*)&lB[srow * 32 + scol] = rb0;
            *(short8*)&lB[(64 + srow) * 32 + scol] = rb1;
        }
        __syncthreads();

        short8 af[4], bf[4];
#pragma unroll
        for (int i = 0; i < 4; i++)
            af[i] = *(const short8*)&lA[(wm + i * 16 + m16) * 32 + quad * 8];
#pragma unroll
        for (int j = 0; j < 4; j++)
            bf[j] = *(const short8*)&lB[(wn + j * 16 + m16) * 32 + quad * 8];
#pragma unroll
        for (int i = 0; i < 4; i++)
#pragma unroll
            for (int j = 0; j < 4; j++)
                acc[i][j] = MFMA16(af[i], bf[j], acc[i][j]);
    }

    const int row0 = bm * 128 + wm + quad * 4;           // includes quad

    if (widx == 2) {
        // V: transposed store. Vt[d][seq], 4 consecutive rows (r) pack to 8B.
#pragma unroll
        for (int i = 0; i < 4; i++)
#pragma unroll
            for (int j = 0; j < 4; j++) {
                const int dcol = bcol0 + wn + j * 16 + m16;
                ushort4 pk;
                pk.x = f2bf(acc[i][j][0]); pk.y = f2bf(acc[i][j][1]);
                pk.z = f2bf(acc[i][j][2]); pk.w = f2bf(acc[i][j][3]);
                *(ushort4*)((unsigned short*)Vt + (int64_t)dcol * 8192 + row0 + i * 16) = pk;
            }
    } else {
        // Q/K: rope in epilogue. Pair partner value lives in lane^1.
        __hip_bfloat16* dst = (widx == 0) ? Qp : Kp;
        const float scale = (widx == 0) ? 0.18033688011112042f /* log2(e)/8 */ : 1.0f;
#pragma unroll
        for (int j = 0; j < 4; j++) {
            const int col = bcol0 + wn + j * 16 + m16;
            const int d = col & 63;
            const int fi = d >> 1;
            const bool evn = (d & 1) == 0;
            const float f = exp2f(-(float)fi * (13.287712379549449f / 32.0f));
#pragma unroll
            for (int i = 0; i < 4; i++)
#pragma unroll
                for (int r = 0; r < 4; r++) {
                    const float v = acc[i][j][r];
                    const float p = __shfl_xor(v, 1);
                    const int row = row0 + i * 16 + r;
                    float sn, cs;
                    sincosf((float)(row & 2047) * f, &sn, &cs);
                    const float o = evn ? (v * cs - p * sn) : (p * sn + v * cs);
                    dst[(int64_t)row * 1024 + col] = __float2bfloat16(o * scale);
                }
        }
    }
}

// ---------------------------------------------------------------------------
// Output GEMM: C[M][N] = A[M][K] * B[N][K]^T, A bf16, B bf16 or fp32, C fp32.
// ---------------------------------------------------------------------------
template<int BBF>
__global__ __launch_bounds__(256) void gemm_o(
    const __hip_bfloat16* __restrict__ Abf, const void* __restrict__ B,
    float* __restrict__ C, int M, int N, int K)
{
    __shared__ __hip_bfloat16 lA[128 * 32];
    __shared__ __hip_bfloat16 lB[128 * 32];

    const int nb = N >> 7;
    const int bm = blockIdx.x / nb, bn = blockIdx.x % nb;
    const int tid = threadIdx.x;
    const int wave = tid >> 6, lane = tid & 63;
    const int wm = (wave >> 1) * 64, wn = (wave & 1) * 64;
    const int m16 = lane & 15, quad = lane >> 4;
    const int lrow = lane >> 2, lcol = (lane & 3) * 8;
    const int srow = tid >> 2, scol = (tid & 3) * 8;

    float4v acc[4][4] = {};

    for (int k0 = 0; k0 < K; k0 += 32) {
        short8 rb0, rb1;
        if (!BBF) {
            const float* Bf = (const float*)B;
            rb0 = load8f(Bf + (int64_t)(bn * 128 + srow) * K + scol + k0);
            rb1 = load8f(Bf + (int64_t)(bn * 128 + 64 + srow) * K + scol + k0);
        }
        __syncthreads();
        {
            const __hip_bfloat16* g = Abf + (int64_t)(bm * 128 + wave * 32 + lrow) * K + lcol + k0;
            glds16(g, &lA[wave * 1024]);
            glds16(g + (int64_t)16 * K, &lA[wave * 1024 + 512]);
        }
        if (BBF) {
            const __hip_bfloat16* g = (const __hip_bfloat16*)B +
                (int64_t)(bn * 128 + wave * 32 + lrow) * K + lcol + k0;
            glds16(g, &lB[wave * 1024]);
            glds16(g + (int64_t)16 * K, &lB[wave * 1024 + 512]);
        } else {
            *(short8*)&lB[srow * 32 + scol] = rb0;
            *(short8*)&lB[(64 + srow) * 32 + scol] = rb1;
        }
        __syncthreads();

        short8 af[4], bf[4];
#pragma unroll
        for (int i = 0; i < 4; i++)
            af[i] = *(const short8*)&lA[(wm + i * 16 + m16) * 32 + quad * 8];
#pragma unroll
        for (int j = 0; j < 4; j++)
            bf[j] = *(const short8*)&lB[(wn + j * 16 + m16) * 32 + quad * 8];
#pragma unroll
        for (int i = 0; i < 4; i++)
#pragma unroll
            for (int j = 0; j < 4; j++)
                acc[i][j] = MFMA16(af[i], bf[j], acc[i][j]);
    }

    const int row0 = bm * 128 + wm + quad * 4;
    const int col0 = bn * 128 + wn + m16;
#pragma unroll
    for (int i = 0; i < 4; i++)
#pragma unroll
        for (int j = 0; j < 4; j++)
#pragma unroll
            for (int r = 0; r < 4; r++)
                C[(int64_t)(row0 + i * 16 + r) * N + col0 + j * 16] = acc[i][j][r];
}

// ---------------------------------------------------------------------------
// Flash attention, causal, fixed-max softmax: Q pre-scaled by log2e/8 so
// p = exp2(score). Block = 4 waves x 32 Q rows = 128; Bc = 64. K/V register
// prefetch for tile kt+1 issued before tile kt's compute. Per-lane l
// partials reduced once at epilogue. blockIdx: qt = >>6, bh = &63 so the 16
// blocks sharing one head's K/V land on the same XCD (mod-8 dispatch).
// LDS XOR swizzle: (row,col) at row*64 + (col ^ ((row&7)*8)).
// ---------------------------------------------------------------------------
__global__ __launch_bounds__(256) void attn_kernel(
    const __hip_bfloat16* __restrict__ Q,
    const __hip_bfloat16* __restrict__ Kg,
    const __hip_bfloat16* __restrict__ Vt,
    __hip_bfloat16* __restrict__ O,
    int S, int BS)
{
    const int qt = blockIdx.x >> 6;
    const int bh = blockIdx.x & 63;
    const int b = bh >> 4, h = bh & 15;
    const int tid = threadIdx.x;
    const int wave = tid >> 6, lane = tid & 63;
    const int m16 = lane & 15, quad = lane >> 4;

    __shared__ __hip_bfloat16 lK[64 * 64];
    __shared__ __hip_bfloat16 lV[64 * 64];        // Vt tile: [d][kv]
    __shared__ __hip_bfloat16 lP[4][32 * 64];

    const int qrow0 = qt * 128 + wave * 32;
    const int64_t rowbase = (int64_t)b * S;

    short8 aq[2][2];
#pragma unroll
    for (int i = 0; i < 2; i++) {
        const __hip_bfloat16* qp = Q + (rowbase + qrow0 + i * 16 + m16) * 1024 + h * 64 + quad * 8;
        aq[i][0] = *(const short8*)qp;
        aq[i][1] = *(const short8*)(qp + 32);
    }

    float lsum[2][4] = {};
    float4v o_acc[2][4] = {};

    const int srow = tid >> 3;
    const int scol = (tid & 7) * 8;

    const int ktmax_blk = 2 * qt + 1;
    const int ktmax_w = 2 * qt + (wave >> 1);

    short8 pk0, pk1, pv0, pv1;
#define PREFETCH(KT)                                                                          \
    do {                                                                                      \
        pk0 = *(const short8*)(Kg + (rowbase + (KT) * 64 + srow) * 1024 + h * 64 + scol);     \
        pk1 = *(const short8*)(Kg + (rowbase + (KT) * 64 + srow + 32) * 1024 + h * 64 + scol);\
        pv0 = *(const short8*)(Vt + (int64_t)(h * 64 + srow) * BS + rowbase + (KT) * 64 + scol);      \
        pv1 = *(const short8*)(Vt + (int64_t)(h * 64 + srow + 32) * BS + rowbase + (KT) * 64 + scol); \
    } while (0)

    PREFETCH(0);

    for (int kt = 0; kt <= ktmax_blk; kt++) {
        __syncthreads();
        *(short8*)&lK[srow * 64 + (scol ^ ((srow & 7) * 8))] = pk0;
        *(short8*)&lK[(srow + 32) * 64 + (scol ^ (((srow + 32) & 7) * 8))] = pk1;
        *(short8*)&lV[srow * 64 + (scol ^ ((srow & 7) * 8))] = pv0;
        *(short8*)&lV[(srow + 32) * 64 + (scol ^ (((srow + 32) & 7) * 8))] = pv1;
        __syncthreads();

        if (kt < ktmax_blk) PREFETCH(kt + 1);

        if (kt <= ktmax_w) {
            // S = Q K^T : 32 x 64 per wave
            float4v sacc[2][4] = {};
#pragma unroll
            for (int jn = 0; jn < 4; jn++) {
                const int n = jn * 16 + m16;
                const int sw = (n & 7) * 8;
                short8 b0 = *(const short8*)&lK[n * 64 + ((quad * 8) ^ sw)];
                short8 b1 = *(const short8*)&lK[n * 64 + ((32 + quad * 8) ^ sw)];
#pragma unroll
                for (int i = 0; i < 2; i++) {
                    sacc[i][jn] = MFMA16(aq[i][0], b0, sacc[i][jn]);
                    sacc[i][jn] = MFMA16(aq[i][1], b1, sacc[i][jn]);
                }
            }

            const bool need_mask = (kt * 64 + 63 > qrow0);
#pragma unroll
            for (int i = 0; i < 2; i++)
#pragma unroll
                for (int jn = 0; jn < 4; jn++) {
                    const int kvg = kt * 64 + jn * 16 + m16;
#pragma unroll
                    for (int r = 0; r < 4; r++) {
                        float p = exp2f(sacc[i][jn][r]);
                        if (need_mask) {
                            const int qg = qrow0 + i * 16 + quad * 4 + r;
                            if (kvg > qg) p = 0.0f;
                        }
                        lsum[i][r] += p;
                        const int row = i * 16 + quad * 4 + r;
                        const int col = jn * 16 + m16;
                        lP[wave][row * 64 + (col ^ ((row & 7) * 8))] = __float2bfloat16(p);
                    }
                }

            // O += P V (lP wave-private: lgkmcnt ordering suffices)
            short8 ap[2][2];
            {
                const int sw = (m16 & 7) * 8;
#pragma unroll
                for (int i = 0; i < 2; i++) {
                    ap[i][0] = *(const short8*)&lP[wave][(i * 16 + m16) * 64 + ((quad * 8) ^ sw)];
                    ap[i][1] = *(const short8*)&lP[wave][(i * 16 + m16) * 64 + ((32 + quad * 8) ^ sw)];
                }
            }
#pragma unroll
            for (int jd = 0; jd < 4; jd++) {
                const int d = jd * 16 + m16;
                const int sw = (d & 7) * 8;
                short8 b0 = *(const short8*)&lV[d * 64 + ((quad * 8) ^ sw)];
                short8 b1 = *(const short8*)&lV[d * 64 + ((32 + quad * 8) ^ sw)];
#pragma unroll
                for (int i = 0; i < 2; i++) {
                    o_acc[i][jd] = MFMA16(ap[i][0], b0, o_acc[i][jd]);
                    o_acc[i][jd] = MFMA16(ap[i][1], b1, o_acc[i][jd]);
                }
            }
        }
    }
#undef PREFETCH

    float rinv[2][4];
#pragma unroll
    for (int i = 0; i < 2; i++)
#pragma unroll
        for (int r = 0; r < 4; r++) {
            float v = lsum[i][r];
#pragma unroll
            for (int off = 1; off < 16; off <<= 1)
                v += __shfl_xor(v, off, 16);
            rinv[i][r] = 1.0f / v;
        }

#pragma unroll
    for (int i = 0; i < 2; i++)
#pragma unroll
        for (int jd = 0; jd < 4; jd++)
#pragma unroll
            for (int r = 0; r < 4; r++) {
                const int row = qrow0 + i * 16 + quad * 4 + r;
                O[(rowbase + row) * 1024 + h * 64 + jd * 16 + m16] =
                    __float2bfloat16(o_acc[i][jd][r] * rinv[i][r]);
            }
}

// ---------------------------------------------------------------------------
extern "C" void kernel_launch(void* const* d_in, const int* in_sizes, int n_in,
                              void* d_out, int out_size, void* d_ws, size_t ws_size,
                              hipStream_t stream)
{
    const float* x  = (const float*)d_in[0];
    const void*  qw = d_in[1];
    const void*  kw = d_in[2];
    const void*  vw = d_in[3];
    const void*  ow = d_in[4];

    const int BS = 8192, D = 1024, S = 2048;
    const size_t MB = 1024 * 1024;

    char* ws = (char*)d_ws;
    __hip_bfloat16* xb  = (__hip_bfloat16*)(ws);
    __hip_bfloat16* Qb  = (__hip_bfloat16*)(ws + 16 * MB);   // also AO
    __hip_bfloat16* Kb  = (__hip_bfloat16*)(ws + 32 * MB);
    __hip_bfloat16* Vtb = (__hip_bfloat16*)(ws + 48 * MB);
    __hip_bfloat16* wqb = (__hip_bfloat16*)(ws + 64 * MB);
    __hip_bfloat16* wkb = (__hip_bfloat16*)(ws + 66 * MB);
    __hip_bfloat16* wvb = (__hip_bfloat16*)(ws + 68 * MB);
    __hip_bfloat16* wob = (__hip_bfloat16*)(ws + 70 * MB);
    const bool wbf = ws_size >= 72 * MB;

    dim3 blk(256);
    convert_kernel<<<(BS * D) / 2048, blk, 0, stream>>>(x, xb);
    if (wbf) {
        convert_kernel<<<(D * D) / 2048, blk, 0, stream>>>((const float*)qw, wqb);
        convert_kernel<<<(D * D) / 2048, blk, 0, stream>>>((const float*)kw, wkb);
        convert_kernel<<<(D * D) / 2048, blk, 0, stream>>>((const float*)vw, wvb);
        convert_kernel<<<(D * D) / 2048, blk, 0, stream>>>((const float*)ow, wob);
        qkv_gemm<1><<<64 * 24, blk, 0, stream>>>(xb, wqb, wkb, wvb, Qb, Kb, Vtb);
    } else {
        qkv_gemm<0><<<64 * 24, blk, 0, stream>>>(xb, qw, kw, vw, Qb, Kb, Vtb);
    }
    attn_kernel<<<4 * 16 * (S / 128), blk, 0, stream>>>(Qb, Kb, Vtb, Qb /*AO*/, S, BS);
    if (wbf) gemm_o<1><<<(BS / 128) * (D / 128), blk, 0, stream>>>(Qb, wob, (float*)d_out, BS, D, D);
    else     gemm_o<0><<<(BS / 128) * (D / 128), blk, 0, stream>>>(Qb, ow,  (float*)d_out, BS, D, D);
}

// Round 6
// 352.445 us; speedup vs baseline: 2.8910x; 2.8910x over previous
//
#include <hip/hip_runtime.h>
#include <hip/hip_bf16.h>
#include <cstdint>

// B=4, S=2048, D=1024, NH=16, DK=64. Inputs fp32, output fp32.
// Pipeline:
//   convert: xb = bf16(x)
//   qkv_gemm (fused, 1536 blocks): Q|K plain bf16 stores; V -> LDS-transpose
//            epilogue -> Vt[1024][8192] (coalesced).
//   rope_table: table[2048][32] = (cos,sin)  (written into xb's dead buffer)
//   rope(Q, scale=log2e/8), rope(K, scale=1)   — table-based, no sincosf
//   attn: causal flash, fixed-max exp2 softmax, K/V register prefetch,
//         Br=128/block (32/wave), Bc=64, AO aliases Q, XCD-friendly swizzle.
//   gemm_o: out = AO @ o_proj^T -> fp32
//
// R5 post-mortem: 16.8M sincosf calls in a GEMM epilogue caused 3.16 GB of
// scratch writes (WRITE_SIZE counter) — never call libm sincos in hot code.

typedef __attribute__((ext_vector_type(8))) short short8;
typedef __attribute__((ext_vector_type(4))) float float4v;

#define MFMA16(a, b, c) __builtin_amdgcn_mfma_f32_16x16x32_bf16((a), (b), (c), 0, 0, 0)

__device__ __forceinline__ void glds16(const void* g, void* l) {
    __builtin_amdgcn_global_load_lds(
        (const __attribute__((address_space(1))) void*)g,
        (__attribute__((address_space(3))) void*)l, 16, 0, 0);
}

__device__ __forceinline__ unsigned short f2bf(float x) {
    union { float f; unsigned int u; } v; v.f = x;
    unsigned int r = (v.u + 0x7FFFu + ((v.u >> 16) & 1u)) >> 16;   // RNE
    return (unsigned short)r;
}

__device__ __forceinline__ float bf2f(unsigned short b) {
    union { unsigned int u; float f; } v; v.u = ((unsigned int)b) << 16;
    return v.f;
}

__device__ __forceinline__ short8 load8f(const float* p) {
    const float4 f0 = *(const float4*)p;
    const float4 f1 = *(const float4*)(p + 4);
    short8 r;
    r[0] = (short)f2bf(f0.x); r[1] = (short)f2bf(f0.y);
    r[2] = (short)f2bf(f0.z); r[3] = (short)f2bf(f0.w);
    r[4] = (short)f2bf(f1.x); r[5] = (short)f2bf(f1.y);
    r[6] = (short)f2bf(f1.z); r[7] = (short)f2bf(f1.w);
    return r;
}

// ---------------------------------------------------------------------------
__global__ __launch_bounds__(256) void convert_kernel(
    const float* __restrict__ in, __hip_bfloat16* __restrict__ out)
{
    const int idx = (blockIdx.x * 256 + threadIdx.x) * 8;
    *(short8*)(out + idx) = load8f(in + idx);
}

// ---------------------------------------------------------------------------
// Rope table: table[pos][fi] = (cos(pos*f), sin(pos*f)), pos<2048, fi<32.
// 65536 sincosf calls total — cold path, negligible.
// ---------------------------------------------------------------------------
__global__ __launch_bounds__(256) void rope_table_kernel(float2* __restrict__ table)
{
    const int idx = blockIdx.x * 256 + threadIdx.x;   // 65536
    const int pos = idx >> 5, fi = idx & 31;
    const float f = exp2f(-(float)fi * (13.287712379549449f / 32.0f));
    float sn, cs;
    sincosf((float)pos * f, &sn, &cs);
    table[idx] = make_float2(cs, sn);
}

// ---------------------------------------------------------------------------
// Rope in place on T[8192][1024]; pairs (2i,2i+1) within each 64-dim head,
// pos = row % 2048. Table-based. scale folds log2(e)/8 into Q.
// ---------------------------------------------------------------------------
__global__ __launch_bounds__(256) void rope_kernel(
    __hip_bfloat16* __restrict__ T, const float2* __restrict__ table, float scale)
{
    const int idx = blockIdx.x * 256 + threadIdx.x;   // 8192*512 total
    const int r = idx >> 9;
    const int p = idx & 511;
    const int h = p >> 5, i = p & 31;
    const float2 cs = table[(r & 2047) * 32 + i];
    unsigned short* ptr = (unsigned short*)T + (int64_t)r * 1024 + h * 64 + 2 * i;
    const ushort2 xv = *(const ushort2*)ptr;
    const float x1 = bf2f(xv.x), x2 = bf2f(xv.y);
    ushort2 o;
    o.x = f2bf((x1 * cs.x - x2 * cs.y) * scale);
    o.y = f2bf((x1 * cs.y + x2 * cs.x) * scale);
    *(ushort2*)ptr = o;
}

// ---------------------------------------------------------------------------
// Fused QKV GEMM. A = xb [8192 x 1024] bf16 (glds16 staging). B = one of
// {wq,wk,wv} [1024 x 1024] fp32 (register-convert staging). 128x128 tile,
// BK=32, 4 waves, 16x16x32 MFMA, 4x4/wave. widx = bn>>3 selects Q/K/V.
// Q/K: plain bf16 C store (R4-proven). V: LDS-transpose epilogue -> Vt
// (fully coalesced 16B/lane stores). smem overlaid: staging (8192 ushort
// lA + 8192 lB) vs transpose tile (128 x 132 ushort).
// ---------------------------------------------------------------------------
__global__ __launch_bounds__(256) void qkv_gemm(
    const __hip_bfloat16* __restrict__ Abf,
    const float* __restrict__ Wq, const float* __restrict__ Wk, const float* __restrict__ Wv,
    __hip_bfloat16* __restrict__ Qp, __hip_bfloat16* __restrict__ Kp,
    __hip_bfloat16* __restrict__ Vt)
{
    __shared__ unsigned short smem[128 * 132];   // 33792 B
    // staging view: lA = smem[0..4095], lB = smem[4096..8191] (bf16 elems)

    const int K = 1024;
    const int bm = blockIdx.x / 24, bn = blockIdx.x % 24;
    const int widx = bn >> 3;              // 0=Q 1=K 2=V
    const int bcol0 = (bn & 7) * 128;
    const float* W = (widx == 0) ? Wq : (widx == 1) ? Wk : Wv;

    const int tid = threadIdx.x;
    const int wave = tid >> 6, lane = tid & 63;
    const int wm = (wave >> 1) * 64, wn = (wave & 1) * 64;
    const int m16 = lane & 15, quad = lane >> 4;

    const int lrow = lane >> 2, lcol = (lane & 3) * 8;   // glds map
    const int srow = tid >> 2, scol = (tid & 3) * 8;     // register-path map

    float4v acc[4][4] = {};

    for (int k0 = 0; k0 < K; k0 += 32) {
        const short8 rb0 = load8f(W + (int64_t)(bcol0 + srow) * K + scol + k0);
        const short8 rb1 = load8f(W + (int64_t)(bcol0 + 64 + srow) * K + scol + k0);
        __syncthreads();
        {
            const __hip_bfloat16* g = Abf + (int64_t)(bm * 128 + wave * 32 + lrow) * K + lcol + k0;
            glds16(g, &smem[wave * 1024]);
            glds16(g + (int64_t)16 * K, &smem[wave * 1024 + 512]);
        }
        *(short8*)&smem[4096 + srow * 32 + scol] = rb0;
        *(short8*)&smem[4096 + (64 + srow) * 32 + scol] = rb1;
        __syncthreads();

        short8 af[4], bf[4];
#pragma unroll
        for (int i = 0; i < 4; i++)
            af[i] = *(const short8*)&smem[(wm + i * 16 + m16) * 32 + quad * 8];
#pragma unroll
        for (int j = 0; j < 4; j++)
            bf[j] = *(const short8*)&smem[4096 + (wn + j * 16 + m16) * 32 + quad * 8];
#pragma unroll
        for (int i = 0; i < 4; i++)
#pragma unroll
            for (int j = 0; j < 4; j++)
                acc[i][j] = MFMA16(af[i], bf[j], acc[i][j]);
    }

    if (widx == 2) {
        // ---- V: transpose through LDS, coalesced store to Vt[1024][8192] ----
        __syncthreads();   // staging views dead; reuse smem as [d][seq] tile
#pragma unroll
        for (int i = 0; i < 4; i++)
#pragma unroll
            for (int j = 0; j < 4; j++)
#pragma unroll
                for (int r = 0; r < 4; r++)
                    smem[(wn + j * 16 + m16) * 132 + wm + i * 16 + quad * 4 + r] =
                        f2bf(acc[i][j][r]);
        __syncthreads();
        const int dc = tid >> 4;          // 0..15
        const int seg = (tid & 15) * 8;   // 0..120
#pragma unroll
        for (int pass = 0; pass < 8; pass++) {
            const int dcol = pass * 16 + dc;
            const short8 v = *(const short8*)&smem[dcol * 132 + seg];
            *(short8*)((unsigned short*)Vt + (int64_t)(bcol0 + dcol) * 8192 + bm * 128 + seg) = v;
        }
    } else {
        // ---- Q/K: plain store (C layout: col = lane&15, row = quad*4+r) ----
        __hip_bfloat16* dst = (widx == 0) ? Qp : Kp;
        const int row0 = bm * 128 + wm + quad * 4;
        const int col0 = bcol0 + wn + m16;
#pragma unroll
        for (int i = 0; i < 4; i++)
#pragma unroll
            for (int j = 0; j < 4; j++)
#pragma unroll
                for (int r = 0; r < 4; r++)
                    dst[(int64_t)(row0 + i * 16 + r) * 1024 + col0 + j * 16] =
                        __float2bfloat16(acc[i][j][r]);
    }
}

// ---------------------------------------------------------------------------
// Output GEMM: C[M=8192][N=1024] = A * B^T; A bf16 (glds16), B fp32
// (register-convert), C fp32.
// ---------------------------------------------------------------------------
__global__ __launch_bounds__(256) void gemm_o(
    const __hip_bfloat16* __restrict__ Abf, const float* __restrict__ B,
    float* __restrict__ C, int M, int N, int K)
{
    __shared__ __hip_bfloat16 lA[128 * 32];
    __shared__ __hip_bfloat16 lB[128 * 32];

    const int nb = N >> 7;
    const int bm = blockIdx.x / nb, bn = blockIdx.x % nb;
    const int tid = threadIdx.x;
    const int wave = tid >> 6, lane = tid & 63;
    const int wm = (wave >> 1) * 64, wn = (wave & 1) * 64;
    const int m16 = lane & 15, quad = lane >> 4;
    const int lrow = lane >> 2, lcol = (lane & 3) * 8;
    const int srow = tid >> 2, scol = (tid & 3) * 8;

    float4v acc[4][4] = {};

    for (int k0 = 0; k0 < K; k0 += 32) {
        const short8 rb0 = load8f(B + (int64_t)(bn * 128 + srow) * K + scol + k0);
        const short8 rb1 = load8f(B + (int64_t)(bn * 128 + 64 + srow) * K + scol + k0);
        __syncthreads();
        {
            const __hip_bfloat16* g = Abf + (int64_t)(bm * 128 + wave * 32 + lrow) * K + lcol + k0;
            glds16(g, &lA[wave * 1024]);
            glds16(g + (int64_t)16 * K, &lA[wave * 1024 + 512]);
        }
        *(short8*)&lB[srow * 32 + scol] = rb0;
        *(short8*)&lB[(64 + srow) * 32 + scol] = rb1;
        __syncthreads();

        short8 af[4], bf[4];
#pragma unroll
        for (int i = 0; i < 4; i++)
            af[i] = *(const short8*)&lA[(wm + i * 16 + m16) * 32 + quad * 8];
#pragma unroll
        for (int j = 0; j < 4; j++)
            bf[j] = *(const short8*)&lB[(wn + j * 16 + m16) * 32 + quad * 8];
#pragma unroll
        for (int i = 0; i < 4; i++)
#pragma unroll
            for (int j = 0; j < 4; j++)
                acc[i][j] = MFMA16(af[i], bf[j], acc[i][j]);
    }

    const int row0 = bm * 128 + wm + quad * 4;
    const int col0 = bn * 128 + wn + m16;
#pragma unroll
    for (int i = 0; i < 4; i++)
#pragma unroll
        for (int j = 0; j < 4; j++)
#pragma unroll
            for (int r = 0; r < 4; r++)
                C[(int64_t)(row0 + i * 16 + r) * N + col0 + j * 16] = acc[i][j][r];
}

// ---------------------------------------------------------------------------
// Flash attention, causal, fixed-max softmax: Q pre-scaled by log2e/8 so
// p = exp2(score). Block = 4 waves x 32 Q rows = 128; Bc = 64. K/V register
// prefetch for tile kt+1 issued before tile kt's compute. blockIdx: qt=>>6,
// bh=&63 -> the 16 blocks sharing a head's K/V land on the same XCD (mod-8).
// LDS XOR swizzle: (row,col) at row*64 + (col ^ ((row&7)*8)).
// ---------------------------------------------------------------------------
__global__ __launch_bounds__(256) void attn_kernel(
    const __hip_bfloat16* __restrict__ Q,
    const __hip_bfloat16* __restrict__ Kg,
    const __hip_bfloat16* __restrict__ Vt,
    __hip_bfloat16* __restrict__ O,
    int S, int BS)
{
    const int qt = blockIdx.x >> 6;
    const int bh = blockIdx.x & 63;
    const int b = bh >> 4, h = bh & 15;
    const int tid = threadIdx.x;
    const int wave = tid >> 6, lane = tid & 63;
    const int m16 = lane & 15, quad = lane >> 4;

    __shared__ __hip_bfloat16 lK[64 * 64];
    __shared__ __hip_bfloat16 lV[64 * 64];        // Vt tile: [d][kv]
    __shared__ __hip_bfloat16 lP[4][32 * 64];

    const int qrow0 = qt * 128 + wave * 32;
    const int64_t rowbase = (int64_t)b * S;

    short8 aq[2][2];
#pragma unroll
    for (int i = 0; i < 2; i++) {
        const __hip_bfloat16* qp = Q + (rowbase + qrow0 + i * 16 + m16) * 1024 + h * 64 + quad * 8;
        aq[i][0] = *(const short8*)qp;
        aq[i][1] = *(const short8*)(qp + 32);
    }

    float lsum[2][4] = {};
    float4v o_acc[2][4] = {};

    const int srow = tid >> 3;
    const int scol = (tid & 7) * 8;

    const int ktmax_blk = 2 * qt + 1;
    const int ktmax_w = 2 * qt + (wave >> 1);

    short8 pk0, pk1, pv0, pv1;
#define PREFETCH(KT)                                                                          \
    do {                                                                                      \
        pk0 = *(const short8*)(Kg + (rowbase + (KT) * 64 + srow) * 1024 + h * 64 + scol);     \
        pk1 = *(const short8*)(Kg + (rowbase + (KT) * 64 + srow + 32) * 1024 + h * 64 + scol);\
        pv0 = *(const short8*)(Vt + (int64_t)(h * 64 + srow) * BS + rowbase + (KT) * 64 + scol);      \
        pv1 = *(const short8*)(Vt + (int64_t)(h * 64 + srow + 32) * BS + rowbase + (KT) * 64 + scol); \
    } while (0)

    PREFETCH(0);

    for (int kt = 0; kt <= ktmax_blk; kt++) {
        __syncthreads();
        *(short8*)&lK[srow * 64 + (scol ^ ((srow & 7) * 8))] = pk0;
        *(short8*)&lK[(srow + 32) * 64 + (scol ^ (((srow + 32) & 7) * 8))] = pk1;
        *(short8*)&lV[srow * 64 + (scol ^ ((srow & 7) * 8))] = pv0;
        *(short8*)&lV[(srow + 32) * 64 + (scol ^ (((srow + 32) & 7) * 8))] = pv1;
        __syncthreads();

        if (kt < ktmax_blk) PREFETCH(kt + 1);

        if (kt <= ktmax_w) {
            float4v sacc[2][4] = {};
#pragma unroll
            for (int jn = 0; jn < 4; jn++) {
                const int n = jn * 16 + m16;
                const int sw = (n & 7) * 8;
                short8 b0 = *(const short8*)&lK[n * 64 + ((quad * 8) ^ sw)];
                short8 b1 = *(const short8*)&lK[n * 64 + ((32 + quad * 8) ^ sw)];
#pragma unroll
                for (int i = 0; i < 2; i++) {
                    sacc[i][jn] = MFMA16(aq[i][0], b0, sacc[i][jn]);
                    sacc[i][jn] = MFMA16(aq[i][1], b1, sacc[i][jn]);
                }
            }

            const bool need_mask = (kt * 64 + 63 > qrow0);
#pragma unroll
            for (int i = 0; i < 2; i++)
#pragma unroll
                for (int jn = 0; jn < 4; jn++) {
                    const int kvg = kt * 64 + jn * 16 + m16;
#pragma unroll
                    for (int r = 0; r < 4; r++) {
                        float p = exp2f(sacc[i][jn][r]);
                        if (need_mask) {
                            const int qg = qrow0 + i * 16 + quad * 4 + r;
                            if (kvg > qg) p = 0.0f;
                        }
                        lsum[i][r] += p;
                        const int row = i * 16 + quad * 4 + r;
                        const int col = jn * 16 + m16;
                        lP[wave][row * 64 + (col ^ ((row & 7) * 8))] = __float2bfloat16(p);
                    }
                }

            short8 ap[2][2];
            {
                const int sw = (m16 & 7) * 8;
#pragma unroll
                for (int i = 0; i < 2; i++) {
                    ap[i][0] = *(const short8*)&lP[wave][(i * 16 + m16) * 64 + ((quad * 8) ^ sw)];
                    ap[i][1] = *(const short8*)&lP[wave][(i * 16 + m16) * 64 + ((32 + quad * 8) ^ sw)];
                }
            }
#pragma unroll
            for (int jd = 0; jd < 4; jd++) {
                const int d = jd * 16 + m16;
                const int sw = (d & 7) * 8;
                short8 b0 = *(const short8*)&lV[d * 64 + ((quad * 8) ^ sw)];
                short8 b1 = *(const short8*)&lV[d * 64 + ((32 + quad * 8) ^ sw)];
#pragma unroll
                for (int i = 0; i < 2; i++) {
                    o_acc[i][jd] = MFMA16(ap[i][0], b0, o_acc[i][jd]);
                    o_acc[i][jd] = MFMA16(ap[i][1], b1, o_acc[i][jd]);
                }
            }
        }
    }
#undef PREFETCH

    float rinv[2][4];
#pragma unroll
    for (int i = 0; i < 2; i++)
#pragma unroll
        for (int r = 0; r < 4; r++) {
            float v = lsum[i][r];
#pragma unroll
            for (int off = 1; off < 16; off <<= 1)
                v += __shfl_xor(v, off, 16);
            rinv[i][r] = 1.0f / v;
        }

#pragma unroll
    for (int i = 0; i < 2; i++)
#pragma unroll
        for (int jd = 0; jd < 4; jd++)
#pragma unroll
            for (int r = 0; r < 4; r++) {
                const int row = qrow0 + i * 16 + quad * 4 + r;
                O[(rowbase + row) * 1024 + h * 64 + jd * 16 + m16] =
                    __float2bfloat16(o_acc[i][jd][r] * rinv[i][r]);
            }
}

// ---------------------------------------------------------------------------
extern "C" void kernel_launch(void* const* d_in, const int* in_sizes, int n_in,
                              void* d_out, int out_size, void* d_ws, size_t ws_size,
                              hipStream_t stream)
{
    const float* x  = (const float*)d_in[0];
    const float* qw = (const float*)d_in[1];
    const float* kw = (const float*)d_in[2];
    const float* vw = (const float*)d_in[3];
    const float* ow = (const float*)d_in[4];

    const int BS = 8192, D = 1024, S = 2048;
    const size_t MiB = 1024 * 1024;

    char* ws = (char*)d_ws;
    __hip_bfloat16* xb  = (__hip_bfloat16*)(ws);            // dead after qkv
    __hip_bfloat16* Qb  = (__hip_bfloat16*)(ws + 16 * MiB); // also AO
    __hip_bfloat16* Kb  = (__hip_bfloat16*)(ws + 32 * MiB);
    __hip_bfloat16* Vtb = (__hip_bfloat16*)(ws + 48 * MiB);
    float2* table = (float2*)(ws);                          // overlays dead xb

    dim3 blk(256);
    convert_kernel<<<(BS * D) / 2048, blk, 0, stream>>>(x, xb);
    qkv_gemm<<<64 * 24, blk, 0, stream>>>(xb, qw, kw, vw, Qb, Kb, Vtb);
    rope_table_kernel<<<256, blk, 0, stream>>>(table);      // after qkv: xb dead
    rope_kernel<<<(BS * 512) / 256, blk, 0, stream>>>(Qb, table, 0.18033688011112042f);
    rope_kernel<<<(BS * 512) / 256, blk, 0, stream>>>(Kb, table, 1.0f);
    attn_kernel<<<4 * 16 * (S / 128), blk, 0, stream>>>(Qb, Kb, Vtb, Qb /*AO*/, S, BS);
    gemm_o<<<(BS / 128) * (D / 128), blk, 0, stream>>>(Qb, ow, (float*)d_out, BS, D, D);
}

// Round 7
// 324.954 us; speedup vs baseline: 3.1355x; 1.0846x over previous
//
#include <hip/hip_runtime.h>
#include <hip/hip_bf16.h>
#include <cstdint>

// B=4, S=2048, D=1024, NH=16, DK=64. Inputs fp32, output fp32.
// Pipeline:
//   convert: xb = bf16(x); (fast path) weights -> bf16, 2 MiB each
//   qkv_gemm (fused, 1536 blocks): A glds16; B glds16 (fast) or fp32
//            register-convert via v_cvt_pk_bf16_f32 (fallback).
//            Q|K plain bf16 stores; V -> LDS-transpose -> Vt[1024][8192].
//   rope_table -> rope(Q, scale=log2e/8), rope(K)  (table-based)
//   attn: causal flash, fixed-max exp2 softmax, K/V register prefetch,
//         Br=128/block (32/wave), Bc=64, AO aliases Q.
//   gemm_o: out = AO @ o_proj^T -> fp32
//
// R6 post-mortem: qkv VALUBusy 36% / MfmaUtil 18% — fp32 weight conversion in
// the hot K-loop. R7: packed cvt + (ws permitting) hoist conversion out.

typedef __attribute__((ext_vector_type(8))) short short8;
typedef __attribute__((ext_vector_type(4))) float float4v;

#define MFMA16(a, b, c) __builtin_amdgcn_mfma_f32_16x16x32_bf16((a), (b), (c), 0, 0, 0)

__device__ __forceinline__ void glds16(const void* g, void* l) {
    __builtin_amdgcn_global_load_lds(
        (const __attribute__((address_space(1))) void*)g,
        (__attribute__((address_space(3))) void*)l, 16, 0, 0);
}

__device__ __forceinline__ unsigned int pk2(float a, float b) {
    __hip_bfloat162 h = __float22bfloat162_rn(make_float2(a, b));  // v_cvt_pk_bf16_f32
    union { __hip_bfloat162 h; unsigned int u; } v; v.h = h;
    return v.u;
}

__device__ __forceinline__ unsigned short f2bf(float x) {
    union { float f; unsigned int u; } v; v.f = x;
    unsigned int r = (v.u + 0x7FFFu + ((v.u >> 16) & 1u)) >> 16;   // RNE
    return (unsigned short)r;
}

__device__ __forceinline__ float bf2f(unsigned short b) {
    union { unsigned int u; float f; } v; v.u = ((unsigned int)b) << 16;
    return v.f;
}

// 8 contiguous fp32 -> bf16 bits (packed converts)
__device__ __forceinline__ short8 load8f(const float* p) {
    const float4 f0 = *(const float4*)p;
    const float4 f1 = *(const float4*)(p + 4);
    union { short8 s; unsigned int u[4]; } r;
    r.u[0] = pk2(f0.x, f0.y);
    r.u[1] = pk2(f0.z, f0.w);
    r.u[2] = pk2(f1.x, f1.y);
    r.u[3] = pk2(f1.z, f1.w);
    return r.s;
}

// ---------------------------------------------------------------------------
__global__ __launch_bounds__(256) void convert_kernel(
    const float* __restrict__ in, __hip_bfloat16* __restrict__ out)
{
    const int idx = (blockIdx.x * 256 + threadIdx.x) * 8;
    *(short8*)(out + idx) = load8f(in + idx);
}

// ---------------------------------------------------------------------------
__global__ __launch_bounds__(256) void rope_table_kernel(float2* __restrict__ table)
{
    const int idx = blockIdx.x * 256 + threadIdx.x;   // 65536
    const int pos = idx >> 5, fi = idx & 31;
    const float f = exp2f(-(float)fi * (13.287712379549449f / 32.0f));
    float sn, cs;
    sincosf((float)pos * f, &sn, &cs);
    table[idx] = make_float2(cs, sn);
}

// ---------------------------------------------------------------------------
// Rope in place on T[8192][1024]; pairs (2i,2i+1) per 64-dim head, pos=row%2048.
// ---------------------------------------------------------------------------
__global__ __launch_bounds__(256) void rope_kernel(
    __hip_bfloat16* __restrict__ T, const float2* __restrict__ table, float scale)
{
    const int idx = blockIdx.x * 256 + threadIdx.x;   // 8192*512 total
    const int r = idx >> 9;
    const int p = idx & 511;
    const int h = p >> 5, i = p & 31;
    const float2 cs = table[(r & 2047) * 32 + i];
    unsigned short* ptr = (unsigned short*)T + (int64_t)r * 1024 + h * 64 + 2 * i;
    const ushort2 xv = *(const ushort2*)ptr;
    const float x1 = bf2f(xv.x), x2 = bf2f(xv.y);
    const unsigned int o = pk2((x1 * cs.x - x2 * cs.y) * scale,
                               (x1 * cs.y + x2 * cs.x) * scale);
    *(unsigned int*)ptr = o;
}

// ---------------------------------------------------------------------------
// Fused QKV GEMM. A = xb [8192x1024] bf16 (glds16). B = {wq,wk,wv}[1024x1024]:
// BBF=1 -> bf16, glds16 staging; BBF=0 -> fp32, packed register-convert.
// 128x128 tile, BK=32, 4 waves, 16x16x32 MFMA, 4x4/wave. widx = bn>>3.
// Q/K: plain bf16 store. V: LDS-transpose -> Vt coalesced.
// ---------------------------------------------------------------------------
template<int BBF>
__global__ __launch_bounds__(256) void qkv_gemm(
    const __hip_bfloat16* __restrict__ Abf,
    const void* __restrict__ Wq, const void* __restrict__ Wk, const void* __restrict__ Wv,
    __hip_bfloat16* __restrict__ Qp, __hip_bfloat16* __restrict__ Kp,
    __hip_bfloat16* __restrict__ Vt)
{
    __shared__ unsigned short smem[128 * 132];   // 33792 B; staging uses [0..8191]

    const int K = 1024;
    const int bm = blockIdx.x / 24, bn = blockIdx.x % 24;
    const int widx = bn >> 3;              // 0=Q 1=K 2=V
    const int bcol0 = (bn & 7) * 128;
    const void* W = (widx == 0) ? Wq : (widx == 1) ? Wk : Wv;

    const int tid = threadIdx.x;
    const int wave = tid >> 6, lane = tid & 63;
    const int wm = (wave >> 1) * 64, wn = (wave & 1) * 64;
    const int m16 = lane & 15, quad = lane >> 4;

    const int lrow = lane >> 2, lcol = (lane & 3) * 8;   // glds map
    const int srow = tid >> 2, scol = (tid & 3) * 8;     // register-path map

    float4v acc[4][4] = {};

    for (int k0 = 0; k0 < K; k0 += 32) {
        short8 rb0, rb1;
        if (!BBF) {
            const float* Wf = (const float*)W;
            rb0 = load8f(Wf + (int64_t)(bcol0 + srow) * K + scol + k0);
            rb1 = load8f(Wf + (int64_t)(bcol0 + 64 + srow) * K + scol + k0);
        }
        __syncthreads();
        {
            const __hip_bfloat16* g = Abf + (int64_t)(bm * 128 + wave * 32 + lrow) * K + lcol + k0;
            glds16(g, &smem[wave * 1024]);
            glds16(g + (int64_t)16 * K, &smem[wave * 1024 + 512]);
        }
        if (BBF) {
            const __hip_bfloat16* g = (const __hip_bfloat16*)W +
                (int64_t)(bcol0 + wave * 32 + lrow) * K + lcol + k0;
            glds16(g, &smem[4096 + wave * 1024]);
            glds16(g + (int64_t)16 * K, &smem[4096 + wave * 1024 + 512]);
        } else {
            *(short8*)&smem[4096 + srow * 32 + scol] = rb0;
            *(short8*)&smem[4096 + (64 + srow) * 32 + scol] = rb1;
        }
        __syncthreads();

        short8 af[4], bf[4];
#pragma unroll
        for (int i = 0; i < 4; i++)
            af[i] = *(const short8*)&smem[(wm + i * 16 + m16) * 32 + quad * 8];
#pragma unroll
        for (int j = 0; j < 4; j++)
            bf[j] = *(const short8*)&smem[4096 + (wn + j * 16 + m16) * 32 + quad * 8];
#pragma unroll
        for (int i = 0; i < 4; i++)
#pragma unroll
            for (int j = 0; j < 4; j++)
                acc[i][j] = MFMA16(af[i], bf[j], acc[i][j]);
    }

    if (widx == 2) {
        // ---- V: transpose through LDS, coalesced store to Vt[1024][8192] ----
        __syncthreads();
#pragma unroll
        for (int i = 0; i < 4; i++)
#pragma unroll
            for (int j = 0; j < 4; j++)
#pragma unroll
                for (int r = 0; r < 4; r++)
                    smem[(wn + j * 16 + m16) * 132 + wm + i * 16 + quad * 4 + r] =
                        f2bf(acc[i][j][r]);
        __syncthreads();
        const int dc = tid >> 4;          // 0..15
        const int seg = (tid & 15) * 8;   // 0..120
#pragma unroll
        for (int pass = 0; pass < 8; pass++) {
            const int dcol = pass * 16 + dc;
            const short8 v = *(const short8*)&smem[dcol * 132 + seg];
            *(short8*)((unsigned short*)Vt + (int64_t)(bcol0 + dcol) * 8192 + bm * 128 + seg) = v;
        }
    } else {
        // ---- Q/K: plain store (C layout: col = lane&15, row = quad*4+r) ----
        __hip_bfloat16* dst = (widx == 0) ? Qp : Kp;
        const int row0 = bm * 128 + wm + quad * 4;
        const int col0 = bcol0 + wn + m16;
#pragma unroll
        for (int i = 0; i < 4; i++)
#pragma unroll
            for (int j = 0; j < 4; j++)
#pragma unroll
                for (int r = 0; r < 4; r++)
                    dst[(int64_t)(row0 + i * 16 + r) * 1024 + col0 + j * 16] =
                        __float2bfloat16(acc[i][j][r]);
    }
}

// ---------------------------------------------------------------------------
// Output GEMM: C[8192][1024] fp32 = A(bf16, glds16) * B^T; BBF as above.
// ---------------------------------------------------------------------------
template<int BBF>
__global__ __launch_bounds__(256) void gemm_o(
    const __hip_bfloat16* __restrict__ Abf, const void* __restrict__ B,
    float* __restrict__ C, int M, int N, int K)
{
    __shared__ __hip_bfloat16 lA[128 * 32];
    __shared__ __hip_bfloat16 lB[128 * 32];

    const int nb = N >> 7;
    const int bm = blockIdx.x / nb, bn = blockIdx.x % nb;
    const int tid = threadIdx.x;
    const int wave = tid >> 6, lane = tid & 63;
    const int wm = (wave >> 1) * 64, wn = (wave & 1) * 64;
    const int m16 = lane & 15, quad = lane >> 4;
    const int lrow = lane >> 2, lcol = (lane & 3) * 8;
    const int srow = tid >> 2, scol = (tid & 3) * 8;

    float4v acc[4][4] = {};

    for (int k0 = 0; k0 < K; k0 += 32) {
        short8 rb0, rb1;
        if (!BBF) {
            const float* Bf = (const float*)B;
            rb0 = load8f(Bf + (int64_t)(bn * 128 + srow) * K + scol + k0);
            rb1 = load8f(Bf + (int64_t)(bn * 128 + 64 + srow) * K + scol + k0);
        }
        __syncthreads();
        {
            const __hip_bfloat16* g = Abf + (int64_t)(bm * 128 + wave * 32 + lrow) * K + lcol + k0;
            glds16(g, &lA[wave * 1024]);
            glds16(g + (int64_t)16 * K, &lA[wave * 1024 + 512]);
        }
        if (BBF) {
            const __hip_bfloat16* g = (const __hip_bfloat16*)B +
                (int64_t)(bn * 128 + wave * 32 + lrow) * K + lcol + k0;
            glds16(g, &lB[wave * 1024]);
            glds16(g + (int64_t)16 * K, &lB[wave * 1024 + 512]);
        } else {
            *(short8*)&lB[srow * 32 + scol] = rb0;
            *(short8*)&lB[(64 + srow) * 32 + scol] = rb1;
        }
        __syncthreads();

        short8 af[4], bf[4];
#pragma unroll
        for (int i = 0; i < 4; i++)
            af[i] = *(const short8*)&lA[(wm + i * 16 + m16) * 32 + quad * 8];
#pragma unroll
        for (int j = 0; j < 4; j++)
            bf[j] = *(const short8*)&lB[(wn + j * 16 + m16) * 32 + quad * 8];
#pragma unroll
        for (int i = 0; i < 4; i++)
#pragma unroll
            for (int j = 0; j < 4; j++)
                acc[i][j] = MFMA16(af[i], bf[j], acc[i][j]);
    }

    const int row0 = bm * 128 + wm + quad * 4;
    const int col0 = bn * 128 + wn + m16;
#pragma unroll
    for (int i = 0; i < 4; i++)
#pragma unroll
        for (int j = 0; j < 4; j++)
#pragma unroll
            for (int r = 0; r < 4; r++)
                C[(int64_t)(row0 + i * 16 + r) * N + col0 + j * 16] = acc[i][j][r];
}

// ---------------------------------------------------------------------------
// Flash attention, causal, fixed-max softmax: Q pre-scaled by log2e/8 so
// p = exp2(score). Block = 4 waves x 32 Q rows = 128; Bc = 64. K/V register
// prefetch. qt = blockIdx>>6, bh = blockIdx&63 (same-head blocks share XCD).
// LDS XOR swizzle: (row,col) at row*64 + (col ^ ((row&7)*8)).
// ---------------------------------------------------------------------------
__global__ __launch_bounds__(256) void attn_kernel(
    const __hip_bfloat16* __restrict__ Q,
    const __hip_bfloat16* __restrict__ Kg,
    const __hip_bfloat16* __restrict__ Vt,
    __hip_bfloat16* __restrict__ O,
    int S, int BS)
{
    const int qt = blockIdx.x >> 6;
    const int bh = blockIdx.x & 63;
    const int b = bh >> 4, h = bh & 15;
    const int tid = threadIdx.x;
    const int wave = tid >> 6, lane = tid & 63;
    const int m16 = lane & 15, quad = lane >> 4;

    __shared__ __hip_bfloat16 lK[64 * 64];
    __shared__ __hip_bfloat16 lV[64 * 64];        // Vt tile: [d][kv]
    __shared__ __hip_bfloat16 lP[4][32 * 64];

    const int qrow0 = qt * 128 + wave * 32;
    const int64_t rowbase = (int64_t)b * S;

    short8 aq[2][2];
#pragma unroll
    for (int i = 0; i < 2; i++) {
        const __hip_bfloat16* qp = Q + (rowbase + qrow0 + i * 16 + m16) * 1024 + h * 64 + quad * 8;
        aq[i][0] = *(const short8*)qp;
        aq[i][1] = *(const short8*)(qp + 32);
    }

    float lsum[2][4] = {};
    float4v o_acc[2][4] = {};

    const int srow = tid >> 3;
    const int scol = (tid & 7) * 8;

    const int ktmax_blk = 2 * qt + 1;
    const int ktmax_w = 2 * qt + (wave >> 1);

    short8 pk0, pk1, pv0, pv1;
#define PREFETCH(KT)                                                                          \
    do {                                                                                      \
        pk0 = *(const short8*)(Kg + (rowbase + (KT) * 64 + srow) * 1024 + h * 64 + scol);     \
        pk1 = *(const short8*)(Kg + (rowbase + (KT) * 64 + srow + 32) * 1024 + h * 64 + scol);\
        pv0 = *(const short8*)(Vt + (int64_t)(h * 64 + srow) * BS + rowbase + (KT) * 64 + scol);      \
        pv1 = *(const short8*)(Vt + (int64_t)(h * 64 + srow + 32) * BS + rowbase + (KT) * 64 + scol); \
    } while (0)

    PREFETCH(0);

    for (int kt = 0; kt <= ktmax_blk; kt++) {
        __syncthreads();
        *(short8*)&lK[srow * 64 + (scol ^ ((srow & 7) * 8))] = pk0;
        *(short8*)&lK[(srow + 32) * 64 + (scol ^ (((srow + 32) & 7) * 8))] = pk1;
        *(short8*)&lV[srow * 64 + (scol ^ ((srow & 7) * 8))] = pv0;
        *(short8*)&lV[(srow + 32) * 64 + (scol ^ (((srow + 32) & 7) * 8))] = pv1;
        __syncthreads();

        if (kt < ktmax_blk) PREFETCH(kt + 1);

        if (kt <= ktmax_w) {
            float4v sacc[2][4] = {};
#pragma unroll
            for (int jn = 0; jn < 4; jn++) {
                const int n = jn * 16 + m16;
                const int sw = (n & 7) * 8;
                short8 b0 = *(const short8*)&lK[n * 64 + ((quad * 8) ^ sw)];
                short8 b1 = *(const short8*)&lK[n * 64 + ((32 + quad * 8) ^ sw)];
#pragma unroll
                for (int i = 0; i < 2; i++) {
                    sacc[i][jn] = MFMA16(aq[i][0], b0, sacc[i][jn]);
                    sacc[i][jn] = MFMA16(aq[i][1], b1, sacc[i][jn]);
                }
            }

            const bool need_mask = (kt * 64 + 63 > qrow0);
#pragma unroll
            for (int i = 0; i < 2; i++)
#pragma unroll
                for (int jn = 0; jn < 4; jn++) {
                    const int kvg = kt * 64 + jn * 16 + m16;
#pragma unroll
                    for (int r = 0; r < 4; r++) {
                        float p = exp2f(sacc[i][jn][r]);
                        if (need_mask) {
                            const int qg = qrow0 + i * 16 + quad * 4 + r;
                            if (kvg > qg) p = 0.0f;
                        }
                        lsum[i][r] += p;
                        const int row = i * 16 + quad * 4 + r;
                        const int col = jn * 16 + m16;
                        lP[wave][row * 64 + (col ^ ((row & 7) * 8))] = __float2bfloat16(p);
                    }
                }

            short8 ap[2][2];
            {
                const int sw = (m16 & 7) * 8;
#pragma unroll
                for (int i = 0; i < 2; i++) {
                    ap[i][0] = *(const short8*)&lP[wave][(i * 16 + m16) * 64 + ((quad * 8) ^ sw)];
                    ap[i][1] = *(const short8*)&lP[wave][(i * 16 + m16) * 64 + ((32 + quad * 8) ^ sw)];
                }
            }
#pragma unroll
            for (int jd = 0; jd < 4; jd++) {
                const int d = jd * 16 + m16;
                const int sw = (d & 7) * 8;
                short8 b0 = *(const short8*)&lV[d * 64 + ((quad * 8) ^ sw)];
                short8 b1 = *(const short8*)&lV[d * 64 + ((32 + quad * 8) ^ sw)];
#pragma unroll
                for (int i = 0; i < 2; i++) {
                    o_acc[i][jd] = MFMA16(ap[i][0], b0, o_acc[i][jd]);
                    o_acc[i][jd] = MFMA16(ap[i][1], b1, o_acc[i][jd]);
                }
            }
        }
    }
#undef PREFETCH

    float rinv[2][4];
#pragma unroll
    for (int i = 0; i < 2; i++)
#pragma unroll
        for (int r = 0; r < 4; r++) {
            float v = lsum[i][r];
#pragma unroll
            for (int off = 1; off < 16; off <<= 1)
                v += __shfl_xor(v, off, 16);
            rinv[i][r] = 1.0f / v;
        }

#pragma unroll
    for (int i = 0; i < 2; i++)
#pragma unroll
        for (int jd = 0; jd < 4; jd++)
#pragma unroll
            for (int r = 0; r < 4; r++) {
                const int row = qrow0 + i * 16 + quad * 4 + r;
                O[(rowbase + row) * 1024 + h * 64 + jd * 16 + m16] =
                    __float2bfloat16(o_acc[i][jd][r] * rinv[i][r]);
            }
}

// ---------------------------------------------------------------------------
extern "C" void kernel_launch(void* const* d_in, const int* in_sizes, int n_in,
                              void* d_out, int out_size, void* d_ws, size_t ws_size,
                              hipStream_t stream)
{
    const float* x  = (const float*)d_in[0];
    const float* qw = (const float*)d_in[1];
    const float* kw = (const float*)d_in[2];
    const float* vw = (const float*)d_in[3];
    const float* ow = (const float*)d_in[4];

    const int BS = 8192, D = 1024, S = 2048;
    const size_t MiB = 1024 * 1024;

    char* ws = (char*)d_ws;
    __hip_bfloat16* xb  = (__hip_bfloat16*)(ws);            // dead after qkv
    __hip_bfloat16* Qb  = (__hip_bfloat16*)(ws + 16 * MiB); // also AO
    __hip_bfloat16* Kb  = (__hip_bfloat16*)(ws + 32 * MiB);
    __hip_bfloat16* Vtb = (__hip_bfloat16*)(ws + 48 * MiB);
    __hip_bfloat16* wqb = (__hip_bfloat16*)(ws + 64 * MiB);
    __hip_bfloat16* wkb = (__hip_bfloat16*)(ws + 66 * MiB);
    __hip_bfloat16* wvb = (__hip_bfloat16*)(ws + 68 * MiB);
    __hip_bfloat16* wob = (__hip_bfloat16*)(ws + 70 * MiB);
    float2* table = (float2*)(ws);                          // overlays dead xb
    const bool wbf = ws_size >= 72 * MiB;                   // fast path fits?

    dim3 blk(256);
    convert_kernel<<<(BS * D) / 2048, blk, 0, stream>>>(x, xb);
    if (wbf) {
        convert_kernel<<<(D * D) / 2048, blk, 0, stream>>>(qw, wqb);
        convert_kernel<<<(D * D) / 2048, blk, 0, stream>>>(kw, wkb);
        convert_kernel<<<(D * D) / 2048, blk, 0, stream>>>(vw, wvb);
        convert_kernel<<<(D * D) / 2048, blk, 0, stream>>>(ow, wob);
        qkv_gemm<1><<<64 * 24, blk, 0, stream>>>(xb, wqb, wkb, wvb, Qb, Kb, Vtb);
    } else {
        qkv_gemm<0><<<64 * 24, blk, 0, stream>>>(xb, qw, kw, vw, Qb, Kb, Vtb);
    }
    rope_table_kernel<<<256, blk, 0, stream>>>(table);      // after qkv: xb dead
    rope_kernel<<<(BS * 512) / 256, blk, 0, stream>>>(Qb, table, 0.18033688011112042f);
    rope_kernel<<<(BS * 512) / 256, blk, 0, stream>>>(Kb, table, 1.0f);
    attn_kernel<<<4 * 16 * (S / 128), blk, 0, stream>>>(Qb, Kb, Vtb, Qb /*AO*/, S, BS);
    if (wbf) gemm_o<1><<<(BS / 128) * (D / 128), blk, 0, stream>>>(Qb, wob, (float*)d_out, BS, D, D);
    else     gemm_o<0><<<(BS / 128) * (D / 128), blk, 0, stream>>>(Qb, ow,  (float*)d_out, BS, D, D);
}

// Round 8
// 319.855 us; speedup vs baseline: 3.1855x; 1.0159x over previous
//
#include <hip/hip_runtime.h>
#include <hip/hip_bf16.h>
#include <cstdint>

// B=4, S=2048, D=1024, NH=16, DK=64. Inputs fp32, output fp32.
// Pipeline:
//   convert: xb = bf16(x); weights -> bf16 (fast path, ws >= 72 MiB)
//   qkv_gemm (fused, 1536 blocks): Q|K plain bf16 stores; V -> LDS-transpose
//            -> Vt[1024][8192].
//   rope_table -> rope(Q, scale=log2e/8), rope(K)  (table-based)
//   attn: causal flash, fixed-max exp2 softmax, S^T-MFMA (K,Q operand swap)
//         so P packs to b64 LDS writes; Br=128/block, Bc=64; AO aliases Q.
//   gemm_o: out = AO @ o_proj^T -> fp32
//
// R7 post-mortem: attn VALU-bound (46% VALUBusy) on the P C-layout->A-layout
// LDS round-trip (scalar cvt + b16 writes + per-r swizzle recompute). R8:
// compute S^T instead — C-layout then holds 4 consecutive kv per register,
// enabling pk-convert + ds_write_b64 with r-invariant swizzle.

typedef __attribute__((ext_vector_type(8))) short short8;
typedef __attribute__((ext_vector_type(4))) float float4v;

#define MFMA16(a, b, c) __builtin_amdgcn_mfma_f32_16x16x32_bf16((a), (b), (c), 0, 0, 0)

__device__ __forceinline__ void glds16(const void* g, void* l) {
    __builtin_amdgcn_global_load_lds(
        (const __attribute__((address_space(1))) void*)g,
        (__attribute__((address_space(3))) void*)l, 16, 0, 0);
}

__device__ __forceinline__ unsigned int pk2(float a, float b) {
    __hip_bfloat162 h = __float22bfloat162_rn(make_float2(a, b));  // v_cvt_pk_bf16_f32
    union { __hip_bfloat162 h; unsigned int u; } v; v.h = h;
    return v.u;
}

__device__ __forceinline__ unsigned short f2bf(float x) {
    union { float f; unsigned int u; } v; v.f = x;
    unsigned int r = (v.u + 0x7FFFu + ((v.u >> 16) & 1u)) >> 16;   // RNE
    return (unsigned short)r;
}

__device__ __forceinline__ float bf2f(unsigned short b) {
    union { unsigned int u; float f; } v; v.u = ((unsigned int)b) << 16;
    return v.f;
}

// 8 contiguous fp32 -> bf16 bits (packed converts)
__device__ __forceinline__ short8 load8f(const float* p) {
    const float4 f0 = *(const float4*)p;
    const float4 f1 = *(const float4*)(p + 4);
    union { short8 s; unsigned int u[4]; } r;
    r.u[0] = pk2(f0.x, f0.y);
    r.u[1] = pk2(f0.z, f0.w);
    r.u[2] = pk2(f1.x, f1.y);
    r.u[3] = pk2(f1.z, f1.w);
    return r.s;
}

// ---------------------------------------------------------------------------
__global__ __launch_bounds__(256) void convert_kernel(
    const float* __restrict__ in, __hip_bfloat16* __restrict__ out)
{
    const int idx = (blockIdx.x * 256 + threadIdx.x) * 8;
    *(short8*)(out + idx) = load8f(in + idx);
}

// ---------------------------------------------------------------------------
__global__ __launch_bounds__(256) void rope_table_kernel(float2* __restrict__ table)
{
    const int idx = blockIdx.x * 256 + threadIdx.x;   // 65536
    const int pos = idx >> 5, fi = idx & 31;
    const float f = exp2f(-(float)fi * (13.287712379549449f / 32.0f));
    float sn, cs;
    sincosf((float)pos * f, &sn, &cs);
    table[idx] = make_float2(cs, sn);
}

// ---------------------------------------------------------------------------
// Rope in place on T[8192][1024]; pairs (2i,2i+1) per 64-dim head, pos=row%2048.
// ---------------------------------------------------------------------------
__global__ __launch_bounds__(256) void rope_kernel(
    __hip_bfloat16* __restrict__ T, const float2* __restrict__ table, float scale)
{
    const int idx = blockIdx.x * 256 + threadIdx.x;   // 8192*512 total
    const int r = idx >> 9;
    const int p = idx & 511;
    const int h = p >> 5, i = p & 31;
    const float2 cs = table[(r & 2047) * 32 + i];
    unsigned short* ptr = (unsigned short*)T + (int64_t)r * 1024 + h * 64 + 2 * i;
    const ushort2 xv = *(const ushort2*)ptr;
    const float x1 = bf2f(xv.x), x2 = bf2f(xv.y);
    const unsigned int o = pk2((x1 * cs.x - x2 * cs.y) * scale,
                               (x1 * cs.y + x2 * cs.x) * scale);
    *(unsigned int*)ptr = o;
}

// ---------------------------------------------------------------------------
// Fused QKV GEMM. A = xb [8192x1024] bf16 (glds16). B = {wq,wk,wv}[1024x1024]:
// BBF=1 -> bf16 glds16; BBF=0 -> fp32 packed register-convert.
// Q/K: plain bf16 store. V: LDS-transpose -> Vt coalesced.
// ---------------------------------------------------------------------------
template<int BBF>
__global__ __launch_bounds__(256) void qkv_gemm(
    const __hip_bfloat16* __restrict__ Abf,
    const void* __restrict__ Wq, const void* __restrict__ Wk, const void* __restrict__ Wv,
    __hip_bfloat16* __restrict__ Qp, __hip_bfloat16* __restrict__ Kp,
    __hip_bfloat16* __restrict__ Vt)
{
    __shared__ unsigned short smem[128 * 132];   // 33792 B; staging uses [0..8191]

    const int K = 1024;
    const int bm = blockIdx.x / 24, bn = blockIdx.x % 24;
    const int widx = bn >> 3;              // 0=Q 1=K 2=V
    const int bcol0 = (bn & 7) * 128;
    const void* W = (widx == 0) ? Wq : (widx == 1) ? Wk : Wv;

    const int tid = threadIdx.x;
    const int wave = tid >> 6, lane = tid & 63;
    const int wm = (wave >> 1) * 64, wn = (wave & 1) * 64;
    const int m16 = lane & 15, quad = lane >> 4;

    const int lrow = lane >> 2, lcol = (lane & 3) * 8;   // glds map
    const int srow = tid >> 2, scol = (tid & 3) * 8;     // register-path map

    float4v acc[4][4] = {};

    for (int k0 = 0; k0 < K; k0 += 32) {
        short8 rb0, rb1;
        if (!BBF) {
            const float* Wf = (const float*)W;
            rb0 = load8f(Wf + (int64_t)(bcol0 + srow) * K + scol + k0);
            rb1 = load8f(Wf + (int64_t)(bcol0 + 64 + srow) * K + scol + k0);
        }
        __syncthreads();
        {
            const __hip_bfloat16* g = Abf + (int64_t)(bm * 128 + wave * 32 + lrow) * K + lcol + k0;
            glds16(g, &smem[wave * 1024]);
            glds16(g + (int64_t)16 * K, &smem[wave * 1024 + 512]);
        }
        if (BBF) {
            const __hip_bfloat16* g = (const __hip_bfloat16*)W +
                (int64_t)(bcol0 + wave * 32 + lrow) * K + lcol + k0;
            glds16(g, &smem[4096 + wave * 1024]);
            glds16(g + (int64_t)16 * K, &smem[4096 + wave * 1024 + 512]);
        } else {
            *(short8*)&smem[4096 + srow * 32 + scol] = rb0;
            *(short8*)&smem[4096 + (64 + srow) * 32 + scol] = rb1;
        }
        __syncthreads();

        short8 af[4], bf[4];
#pragma unroll
        for (int i = 0; i < 4; i++)
            af[i] = *(const short8*)&smem[(wm + i * 16 + m16) * 32 + quad * 8];
#pragma unroll
        for (int j = 0; j < 4; j++)
            bf[j] = *(const short8*)&smem[4096 + (wn + j * 16 + m16) * 32 + quad * 8];
#pragma unroll
        for (int i = 0; i < 4; i++)
#pragma unroll
            for (int j = 0; j < 4; j++)
                acc[i][j] = MFMA16(af[i], bf[j], acc[i][j]);
    }

    if (widx == 2) {
        // ---- V: transpose through LDS, coalesced store to Vt[1024][8192] ----
        __syncthreads();
#pragma unroll
        for (int i = 0; i < 4; i++)
#pragma unroll
            for (int j = 0; j < 4; j++)
#pragma unroll
                for (int r = 0; r < 4; r++)
                    smem[(wn + j * 16 + m16) * 132 + wm + i * 16 + quad * 4 + r] =
                        f2bf(acc[i][j][r]);
        __syncthreads();
        const int dc = tid >> 4;          // 0..15
        const int seg = (tid & 15) * 8;   // 0..120
#pragma unroll
        for (int pass = 0; pass < 8; pass++) {
            const int dcol = pass * 16 + dc;
            const short8 v = *(const short8*)&smem[dcol * 132 + seg];
            *(short8*)((unsigned short*)Vt + (int64_t)(bcol0 + dcol) * 8192 + bm * 128 + seg) = v;
        }
    } else {
        // ---- Q/K: plain store (C layout: col = lane&15, row = quad*4+r) ----
        __hip_bfloat16* dst = (widx == 0) ? Qp : Kp;
        const int row0 = bm * 128 + wm + quad * 4;
        const int col0 = bcol0 + wn + m16;
#pragma unroll
        for (int i = 0; i < 4; i++)
#pragma unroll
            for (int j = 0; j < 4; j++)
#pragma unroll
                for (int r = 0; r < 4; r++)
                    dst[(int64_t)(row0 + i * 16 + r) * 1024 + col0 + j * 16] =
                        __float2bfloat16(acc[i][j][r]);
    }
}

// ---------------------------------------------------------------------------
// Output GEMM: C[8192][1024] fp32 = A(bf16, glds16) * B^T; BBF as above.
// ---------------------------------------------------------------------------
template<int BBF>
__global__ __launch_bounds__(256) void gemm_o(
    const __hip_bfloat16* __restrict__ Abf, const void* __restrict__ B,
    float* __restrict__ C, int M, int N, int K)
{
    __shared__ __hip_bfloat16 lA[128 * 32];
    __shared__ __hip_bfloat16 lB[128 * 32];

    const int nb = N >> 7;
    const int bm = blockIdx.x / nb, bn = blockIdx.x % nb;
    const int tid = threadIdx.x;
    const int wave = tid >> 6, lane = tid & 63;
    const int wm = (wave >> 1) * 64, wn = (wave & 1) * 64;
    const int m16 = lane & 15, quad = lane >> 4;
    const int lrow = lane >> 2, lcol = (lane & 3) * 8;
    const int srow = tid >> 2, scol = (tid & 3) * 8;

    float4v acc[4][4] = {};

    for (int k0 = 0; k0 < K; k0 += 32) {
        short8 rb0, rb1;
        if (!BBF) {
            const float* Bf = (const float*)B;
            rb0 = load8f(Bf + (int64_t)(bn * 128 + srow) * K + scol + k0);
            rb1 = load8f(Bf + (int64_t)(bn * 128 + 64 + srow) * K + scol + k0);
        }
        __syncthreads();
        {
            const __hip_bfloat16* g = Abf + (int64_t)(bm * 128 + wave * 32 + lrow) * K + lcol + k0;
            glds16(g, &lA[wave * 1024]);
            glds16(g + (int64_t)16 * K, &lA[wave * 1024 + 512]);
        }
        if (BBF) {
            const __hip_bfloat16* g = (const __hip_bfloat16*)B +
                (int64_t)(bn * 128 + wave * 32 + lrow) * K + lcol + k0;
            glds16(g, &lB[wave * 1024]);
            glds16(g + (int64_t)16 * K, &lB[wave * 1024 + 512]);
        } else {
            *(short8*)&lB[srow * 32 + scol] = rb0;
            *(short8*)&lB[(64 + srow) * 32 + scol] = rb1;
        }
        __syncthreads();

        short8 af[4], bf[4];
#pragma unroll
        for (int i = 0; i < 4; i++)
            af[i] = *(const short8*)&lA[(wm + i * 16 + m16) * 32 + quad * 8];
#pragma unroll
        for (int j = 0; j < 4; j++)
            bf[j] = *(const short8*)&lB[(wn + j * 16 + m16) * 32 + quad * 8];
#pragma unroll
        for (int i = 0; i < 4; i++)
#pragma unroll
            for (int j = 0; j < 4; j++)
                acc[i][j] = MFMA16(af[i], bf[j], acc[i][j]);
    }

    const int row0 = bm * 128 + wm + quad * 4;
    const int col0 = bn * 128 + wn + m16;
#pragma unroll
    for (int i = 0; i < 4; i++)
#pragma unroll
        for (int j = 0; j < 4; j++)
#pragma unroll
            for (int r = 0; r < 4; r++)
                C[(int64_t)(row0 + i * 16 + r) * N + col0 + j * 16] = acc[i][j][r];
}

// ---------------------------------------------------------------------------
// Flash attention, causal, fixed-max softmax (Q pre-scaled by log2e/8;
// p = exp2(score)). Block = 4 waves x 32 Q rows = 128; Bc = 64.
// S^T-MFMA: st[mi][ni] = MFMA(K-frag, Q-frag) gives S^T in C-layout, so each
// register quad holds 4 consecutive kv at fixed qrow -> pk2 + ds_write_b64
// into lP[qrow][kv] (XOR swizzle key 8*(qrow&7), r-invariant). PV reads lP
// with the proven 0-conflict b128 pattern. lsum indexed per (ni, m16);
// epilogue: 2 shuffles + 512B LDS redistribution of 1/l.
// ---------------------------------------------------------------------------
__global__ __launch_bounds__(256) void attn_kernel(
    const __hip_bfloat16* __restrict__ Q,
    const __hip_bfloat16* __restrict__ Kg,
    const __hip_bfloat16* __restrict__ Vt,
    __hip_bfloat16* __restrict__ O,
    int S, int BS)
{
    const int qt = blockIdx.x >> 6;
    const int bh = blockIdx.x & 63;
    const int b = bh >> 4, h = bh & 15;
    const int tid = threadIdx.x;
    const int wave = tid >> 6, lane = tid & 63;
    const int m16 = lane & 15, quad = lane >> 4;

    __shared__ __hip_bfloat16 lK[64 * 64];
    __shared__ __hip_bfloat16 lV[64 * 64];        // Vt tile: [d][kv]
    __shared__ __hip_bfloat16 lP[4][32 * 64];
    __shared__ float lsums[4][2][16];

    const int qrow0 = qt * 128 + wave * 32;
    const int64_t rowbase = (int64_t)b * S;

    // Q frags (B-operand of the S^T MFMA): aq[ni][ks]
    short8 aq[2][2];
#pragma unroll
    for (int i = 0; i < 2; i++) {
        const __hip_bfloat16* qp = Q + (rowbase + qrow0 + i * 16 + m16) * 1024 + h * 64 + quad * 8;
        aq[i][0] = *(const short8*)qp;
        aq[i][1] = *(const short8*)(qp + 32);
    }

    float lsum[2] = {0.f, 0.f};                   // per (ni, lane m16) partials
    float4v o_acc[2][4] = {};

    const int srow = tid >> 3;
    const int scol = (tid & 7) * 8;

    const int ktmax_blk = 2 * qt + 1;
    const int ktmax_w = 2 * qt + (wave >> 1);
    const int k8 = (m16 & 7) * 8;                 // lP swizzle key (elems)

    short8 pk0, pk1, pv0, pv1;
#define PREFETCH(KT)                                                                          \
    do {                                                                                      \
        pk0 = *(const short8*)(Kg + (rowbase + (KT) * 64 + srow) * 1024 + h * 64 + scol);     \
        pk1 = *(const short8*)(Kg + (rowbase + (KT) * 64 + srow + 32) * 1024 + h * 64 + scol);\
        pv0 = *(const short8*)(Vt + (int64_t)(h * 64 + srow) * BS + rowbase + (KT) * 64 + scol);      \
        pv1 = *(const short8*)(Vt + (int64_t)(h * 64 + srow + 32) * BS + rowbase + (KT) * 64 + scol); \
    } while (0)

    PREFETCH(0);

    for (int kt = 0; kt <= ktmax_blk; kt++) {
        __syncthreads();
        *(short8*)&lK[srow * 64 + (scol ^ ((srow & 7) * 8))] = pk0;
        *(short8*)&lK[(srow + 32) * 64 + (scol ^ (((srow + 32) & 7) * 8))] = pk1;
        *(short8*)&lV[srow * 64 + (scol ^ ((srow & 7) * 8))] = pv0;
        *(short8*)&lV[(srow + 32) * 64 + (scol ^ (((srow + 32) & 7) * 8))] = pv1;
        __syncthreads();

        if (kt < ktmax_blk) PREFETCH(kt + 1);

        if (kt <= ktmax_w) {
            // S^T = K Q^T : st[mi][ni], C-layout row = kv, col = qrow
            float4v st[4][2] = {};
#pragma unroll
            for (int mi = 0; mi < 4; mi++) {
                const int n = mi * 16 + m16;
                const int sw = (n & 7) * 8;
                short8 k0 = *(const short8*)&lK[n * 64 + ((quad * 8) ^ sw)];
                short8 k1 = *(const short8*)&lK[n * 64 + ((32 + quad * 8) ^ sw)];
#pragma unroll
                for (int ni = 0; ni < 2; ni++) {
                    st[mi][ni] = MFMA16(k0, aq[ni][0], st[mi][ni]);
                    st[mi][ni] = MFMA16(k1, aq[ni][1], st[mi][ni]);
                }
            }

            // exp2, causal mask, lsum partials, packed b64 write to lP
            const bool need_mask = (kt * 64 + 63 > qrow0);
#pragma unroll
            for (int ni = 0; ni < 2; ni++) {
                const int qg = qrow0 + ni * 16 + m16;
#pragma unroll
                for (int mi = 0; mi < 4; mi++) {
                    float p[4];
#pragma unroll
                    for (int r = 0; r < 4; r++) {
                        p[r] = exp2f(st[mi][ni][r]);
                        if (need_mask) {
                            const int kvg = kt * 64 + mi * 16 + quad * 4 + r;
                            if (kvg > qg) p[r] = 0.0f;
                        }
                    }
                    lsum[ni] += (p[0] + p[1]) + (p[2] + p[3]);
                    uint2 w;
                    w.x = pk2(p[0], p[1]);
                    w.y = pk2(p[2], p[3]);
                    *(uint2*)&lP[wave][(ni * 16 + m16) * 64 + ((mi * 16 + quad * 4) ^ k8)] = w;
                }
            }

            // O += P V (lP wave-private; lgkmcnt ordering suffices)
            short8 ap[2][2];
#pragma unroll
            for (int i = 0; i < 2; i++)
#pragma unroll
                for (int ks = 0; ks < 2; ks++)
                    ap[i][ks] = *(const short8*)
                        &lP[wave][(i * 16 + m16) * 64 + ((ks * 32 + quad * 8) ^ k8)];
#pragma unroll
            for (int jd = 0; jd < 4; jd++) {
                const int d = jd * 16 + m16;
                const int sw = (d & 7) * 8;
                short8 b0 = *(const short8*)&lV[d * 64 + ((quad * 8) ^ sw)];
                short8 b1 = *(const short8*)&lV[d * 64 + ((32 + quad * 8) ^ sw)];
#pragma unroll
                for (int i = 0; i < 2; i++) {
                    o_acc[i][jd] = MFMA16(ap[i][0], b0, o_acc[i][jd]);
                    o_acc[i][jd] = MFMA16(ap[i][1], b1, o_acc[i][jd]);
                }
            }
        }
    }
#undef PREFETCH

    // l reduction: sum across the 4 quads (lanes m16, m16+16, m16+32, m16+48)
#pragma unroll
    for (int ni = 0; ni < 2; ni++) {
        float v = lsum[ni];
        v += __shfl_xor(v, 16);
        v += __shfl_xor(v, 32);
        if (quad == 0) lsums[wave][ni][m16] = 1.0f / v;
    }
    // redistribute 1/l to O-store lanes (wave-private LDS; no barrier needed)
    float ri[2][4];
#pragma unroll
    for (int i = 0; i < 2; i++)
#pragma unroll
        for (int r = 0; r < 4; r++)
            ri[i][r] = lsums[wave][i][quad * 4 + r];

#pragma unroll
    for (int i = 0; i < 2; i++)
#pragma unroll
        for (int jd = 0; jd < 4; jd++)
#pragma unroll
            for (int r = 0; r < 4; r++) {
                const int row = qrow0 + i * 16 + quad * 4 + r;
                O[(rowbase + row) * 1024 + h * 64 + jd * 16 + m16] =
                    __float2bfloat16(o_acc[i][jd][r] * ri[i][r]);
            }
}

// ---------------------------------------------------------------------------
extern "C" void kernel_launch(void* const* d_in, const int* in_sizes, int n_in,
                              void* d_out, int out_size, void* d_ws, size_t ws_size,
                              hipStream_t stream)
{
    const float* x  = (const float*)d_in[0];
    const float* qw = (const float*)d_in[1];
    const float* kw = (const float*)d_in[2];
    const float* vw = (const float*)d_in[3];
    const float* ow = (const float*)d_in[4];

    const int BS = 8192, D = 1024, S = 2048;
    const size_t MiB = 1024 * 1024;

    char* ws = (char*)d_ws;
    __hip_bfloat16* xb  = (__hip_bfloat16*)(ws);            // dead after qkv
    __hip_bfloat16* Qb  = (__hip_bfloat16*)(ws + 16 * MiB); // also AO
    __hip_bfloat16* Kb  = (__hip_bfloat16*)(ws + 32 * MiB);
    __hip_bfloat16* Vtb = (__hip_bfloat16*)(ws + 48 * MiB);
    __hip_bfloat16* wqb = (__hip_bfloat16*)(ws + 64 * MiB);
    __hip_bfloat16* wkb = (__hip_bfloat16*)(ws + 66 * MiB);
    __hip_bfloat16* wvb = (__hip_bfloat16*)(ws + 68 * MiB);
    __hip_bfloat16* wob = (__hip_bfloat16*)(ws + 70 * MiB);
    float2* table = (float2*)(ws);                          // overlays dead xb
    const bool wbf = ws_size >= 72 * MiB;                   // fast path fits?

    dim3 blk(256);
    convert_kernel<<<(BS * D) / 2048, blk, 0, stream>>>(x, xb);
    if (wbf) {
        convert_kernel<<<(D * D) / 2048, blk, 0, stream>>>(qw, wqb);
        convert_kernel<<<(D * D) / 2048, blk, 0, stream>>>(kw, wkb);
        convert_kernel<<<(D * D) / 2048, blk, 0, stream>>>(vw, wvb);
        convert_kernel<<<(D * D) / 2048, blk, 0, stream>>>(ow, wob);
        qkv_gemm<1><<<64 * 24, blk, 0, stream>>>(xb, wqb, wkb, wvb, Qb, Kb, Vtb);
    } else {
        qkv_gemm<0><<<64 * 24, blk, 0, stream>>>(xb, qw, kw, vw, Qb, Kb, Vtb);
    }
    rope_table_kernel<<<256, blk, 0, stream>>>(table);      // after qkv: xb dead
    rope_kernel<<<(BS * 512) / 256, blk, 0, stream>>>(Qb, table, 0.18033688011112042f);
    rope_kernel<<<(BS * 512) / 256, blk, 0, stream>>>(Kb, table, 1.0f);
    attn_kernel<<<4 * 16 * (S / 128), blk, 0, stream>>>(Qb, Kb, Vtb, Qb /*AO*/, S, BS);
    if (wbf) gemm_o<1><<<(BS / 128) * (D / 128), blk, 0, stream>>>(Qb, wob, (float*)d_out, BS, D, D);
    else     gemm_o<0><<<(BS / 128) * (D / 128), blk, 0, stream>>>(Qb, ow,  (float*)d_out, BS, D, D);
}